// Round 17
// baseline (457.895 us; speedup 1.0000x reference)
//
#include <hip/hip_runtime.h>
#include <stdint.h>

#define INCH 512
#define HIDW 512
#define CATW 2560
#define OUTW 256
#define BN_EPS 1e-5f
#define TS 1024   // scan tile

typedef __bf16 bf16x8 __attribute__((ext_vector_type(8)));
typedef float f32x4 __attribute__((ext_vector_type(4)));

__device__ __forceinline__ unsigned short f2bf(float f) {
  union { float f; unsigned u; } v; v.f = f;
  unsigned r = v.u + 0x7FFFu + ((v.u >> 16) & 1u);   // RNE
  return (unsigned short)(r >> 16);
}

__device__ __forceinline__ float bf2f(unsigned short u) {
  union { unsigned u; float f; } v; v.u = ((unsigned)u) << 16; return v.f;
}

__device__ __forceinline__ void pack4(unsigned short* dst, float a, float b, float c, float d) {
  unsigned lo = (unsigned)f2bf(a) | ((unsigned)f2bf(b) << 16);
  unsigned hi = (unsigned)f2bf(c) | ((unsigned)f2bf(d) << 16);
  *reinterpret_cast<uint2*>(dst) = make_uint2(lo, hi);
}

// ---------------- conversion / packing kernels ----------------

__global__ void cvt_bf16_kernel(const float* __restrict__ in, unsigned short* __restrict__ out, int n4) {
  int g = blockIdx.x * blockDim.x + threadIdx.x;
  if (g >= n4) return;
  int base = g * 4;
  float4 v = *reinterpret_cast<const float4*>(in + base);
  pack4(out + base, v.x, v.y, v.z, v.w);
}

// w1p fragment-order: elem ((z*128 + c)*512 + j)*8 + e  =  W1[z][j][c*8+e]
__global__ void pack_w1p_kernel(const float* __restrict__ Wl, const float* __restrict__ Wr,
                                unsigned short* __restrict__ out) {
  int g = blockIdx.x * blockDim.x + threadIdx.x;
  if (g >= 5 * 128 * 512) return;
  int z = g >> 16;
  int rem = g & 65535;
  int c = rem >> 9;             // 0..127
  int j = rem & 511;
  int kk = c * 8;
  const float* src = (kk < 512) ? (Wl + ((size_t)(z * 512 + j)) * 512 + kk)
                                : (Wr + ((size_t)(z * 512 + j)) * 512 + (kk - 512));
  float4 a = *reinterpret_cast<const float4*>(src);
  float4 b = *reinterpret_cast<const float4*>(src + 4);
  pack4(out + (size_t)g * 8, a.x, a.y, a.z, a.w);
  pack4(out + (size_t)g * 8 + 4, b.x, b.y, b.z, b.w);
}

// w23p fragment-order: elem (c*1024 + j)*8 + e = W23[j][c*8+e]
__global__ void pack_w23p_kernel(const float* __restrict__ Wmu_l, const float* __restrict__ Wlv_l,
                                 const float* __restrict__ Wmu_r, const float* __restrict__ Wlv_r,
                                 unsigned short* __restrict__ out) {
  int g = blockIdx.x * blockDim.x + threadIdx.x;
  if (g >= 320 * 1024) return;
  int c = g >> 10;              // 0..319
  int j = g & 1023;
  const float* row;
  if (j < 256)       row = Wmu_l + (size_t)j * CATW;
  else if (j < 512)  row = Wlv_l + (size_t)(j - 256) * CATW;
  else if (j < 768)  row = Wmu_r + (size_t)(j - 512) * CATW;
  else               row = Wlv_r + (size_t)(j - 768) * CATW;
  const float* src = row + c * 8;
  float4 a = *reinterpret_cast<const float4*>(src);
  float4 b = *reinterpret_cast<const float4*>(src + 4);
  pack4(out + (size_t)g * 8, a.x, a.y, a.z, a.w);
  pack4(out + (size_t)g * 8 + 4, b.x, b.y, b.z, b.w);
}

// ---------------- CSR build: key = dst*5 + rel ----------------

__global__ void hist_kernel(const int* __restrict__ ei, const int* __restrict__ ea,
                            int* __restrict__ cnt, int E) {
  int e = blockIdx.x * 256 + threadIdx.x;
  if (e >= E) return;
  atomicAdd(&cnt[ei[E + e] * 5 + ea[e]], 1);
}

__global__ void scan1_kernel(const int* __restrict__ in, int* __restrict__ out,
                             int* __restrict__ bsum, int n) {
  __shared__ int lds[256];
  int t = threadIdx.x;
  int base = blockIdx.x * TS + t * 4;
  int4 v = make_int4(0, 0, 0, 0);
  if (base + 3 < n) v = *reinterpret_cast<const int4*>(in + base);
  else {
    if (base < n) v.x = in[base];
    if (base + 1 < n) v.y = in[base + 1];
    if (base + 2 < n) v.z = in[base + 2];
    if (base + 3 < n) v.w = in[base + 3];
  }
  int s = v.x + v.y + v.z + v.w;
  lds[t] = s;
  __syncthreads();
  for (int o = 1; o < 256; o <<= 1) {
    int a = (t >= o) ? lds[t - o] : 0;
    __syncthreads();
    lds[t] += a;
    __syncthreads();
  }
  int excl = lds[t] - s;
  if (t == 255) bsum[blockIdx.x] = lds[255];
  int e0 = excl, e1 = e0 + v.x, e2 = e1 + v.y, e3 = e2 + v.z;
  if (base < n) out[base] = e0;
  if (base + 1 < n) out[base + 1] = e1;
  if (base + 2 < n) out[base + 2] = e2;
  if (base + 3 < n) out[base + 3] = e3;
}

__global__ void scan2_kernel(int* __restrict__ bsum, int nb) {   // nb <= 128
  __shared__ int lds[128];
  int t = threadIdx.x;
  int v = (t < nb) ? bsum[t] : 0;
  lds[t] = v;
  __syncthreads();
  for (int o = 1; o < 128; o <<= 1) {
    int a = (t >= o) ? lds[t - o] : 0;
    __syncthreads();
    lds[t] += a;
    __syncthreads();
  }
  if (t < nb) bsum[t] = lds[t] - v;   // exclusive
}

__global__ void scan3_kernel(int* __restrict__ out, const int* __restrict__ bsum,
                             int n, int total) {
  int g = blockIdx.x * 256 + threadIdx.x;
  if (g == 0) out[n] = total;
  int base = g * 4;
  if (base >= n) return;
  int add = bsum[base / TS];
  if (base + 3 < n) {
    int4 v = *reinterpret_cast<int4*>(out + base);
    v.x += add; v.y += add; v.z += add; v.w += add;
    *reinterpret_cast<int4*>(out + base) = v;
  } else {
    for (int q = 0; q < 4 && base + q < n; ++q) out[base + q] += add;
  }
}

__global__ void fill_kernel(const int* __restrict__ ei, const int* __restrict__ ea,
                            const int* __restrict__ offs, int* __restrict__ fillc,
                            int* __restrict__ perm, int E) {
  int e = blockIdx.x * 256 + threadIdx.x;
  if (e >= E) return;
  int key = ei[E + e] * 5 + ea[e];
  int p = atomicAdd(&fillc[key], 1);
  perm[offs[key] + p] = ei[e];   // store src
}

// ---------------- gather kernels (no atomics) ----------------

// one block per node: all 5 relation means, 5KB contiguous write
__global__ void gather1_kernel(const unsigned short* __restrict__ xb, const int* __restrict__ offs,
                               const int* __restrict__ perm, unsigned short* __restrict__ meanb5) {
  int i = blockIdx.x;
  int t = threadIdx.x;
#pragma unroll
  for (int k = 0; k < 5; ++k) {
    int b0 = offs[i * 5 + k], b1 = offs[i * 5 + k + 1];
    float a0 = 0.f, a1 = 0.f, a2 = 0.f, a3 = 0.f;
    for (int e = b0; e < b1; ++e) {
      int s = perm[e];
      ushort4 v = reinterpret_cast<const ushort4*>(xb + (size_t)s * 512)[t];
      a0 += bf2f(v.x); a1 += bf2f(v.y); a2 += bf2f(v.z); a3 += bf2f(v.w);
    }
    float inv = (b1 > b0) ? 1.0f / (float)(b1 - b0) : 0.0f;
    pack4(meanb5 + (size_t)i * CATW + k * 512 + t * 4, a0 * inv, a1 * inv, a2 * inv, a3 * inv);
  }
}

// fused: d_out += segment-mean(z, bf16) + bias   (mu cols 0..255, logvar cols 256..511)
__global__ void gather2_kernel(const unsigned short* __restrict__ zb, const int* __restrict__ offs,
                               const int* __restrict__ perm, float* __restrict__ dout,
                               const float* __restrict__ bmu, const float* __restrict__ blv,
                               int M) {
  int i = blockIdx.x;
  int t = threadIdx.x;
  int b0 = offs[i * 5], b1 = offs[i * 5 + 5];
  float a0 = 0.f, a1 = 0.f, a2 = 0.f, a3 = 0.f;
  for (int e = b0; e < b1; ++e) {
    int s = perm[e];
    ushort4 v = reinterpret_cast<const ushort4*>(zb + (size_t)s * 512)[t];
    a0 += bf2f(v.x); a1 += bf2f(v.y); a2 += bf2f(v.z); a3 += bf2f(v.w);
  }
  float inv = (b1 > b0) ? 1.0f / (float)(b1 - b0) : 1.0f;
  int c = t * 4;
  float* op;
  const float* bp;
  if (c < 256) { op = dout + (size_t)i * OUTW + c; bp = bmu + c; }
  else         { op = dout + (size_t)M * OUTW + (size_t)i * OUTW + (c - 256); bp = blv + (c - 256); }
  float4 y = *reinterpret_cast<float4*>(op);
  float4 b = *reinterpret_cast<const float4*>(bp);
  y.x += a0 * inv + b.x; y.y += a1 * inv + b.y;
  y.z += a2 * inv + b.z; y.w += a3 * inv + b.w;
  *reinterpret_cast<float4*>(op) = y;
}

// ---------------- MFMA GEMM: r16 superstep core, 4x1 wave grid (LDS-read dedup) ----------
// LDS-pipe model (r16 post-mortem): per block K-step LDS service was ds_read 16KB (2x2
// wave grid reads every A element TWICE: wc=0/1 pairs share rows) + gload 8KB = 24KB
// -> 192cy vs 78cy MFMA/SIMD => util cap ~40% (matches measured 31%). Fix: wave wv owns
// rows [wv*32,+32) x ALL 128 cols: af[2] (1x A coverage, 8KB/step), acc[2][8], B frags
// 4->8 per buffer (extra reads hit L2, which is idle). LDS/step: 24->16KB.
// Superstep/ring/wait-order safety identical to r16 (load-count-independent argument).
// MODE 0: z=blockIdx.z; A=[meanb5 z-chunk | xb] (K=1024), B=w1p[z]; bias->ReLU->BN -> hb
// MODE 1: A=hb (K=2560), B=w23p; j<512 -> zb (bf16); j>=512 -> d_out raw
template<int MODE>
__global__ __launch_bounds__(256, 2)
void gemm_kernel(const unsigned short* __restrict__ A,
                 const unsigned short* __restrict__ A2,
                 const unsigned short* __restrict__ B,
                 unsigned short* __restrict__ hOut,
                 unsigned short* __restrict__ zbOut,
                 float* __restrict__ fOut2,
                 const float* __restrict__ p0,   // MODE0: bl5
                 const float* __restrict__ p1,   // MODE0: rmean
                 const float* __restrict__ p2,   // MODE0: rvar
                 const float* __restrict__ p3,   // MODE0: gamma
                 const float* __restrict__ p4,   // MODE0: beta
                 int M)
{
  constexpr int KTOT = (MODE == 0) ? (2 * INCH) : CATW;
  constexpr int KT = KTOT / 32;              // 32 / 80 (divisible by 4)
  constexpr int NBLK = (MODE == 0) ? 4 : 8;  // output cols / 128
  constexpr int NC = (MODE == 0) ? 512 : 1024;   // B col count (fragment-order)

  // bijective XCD-chunked swizzle (m204), col-fastest within an XCD chunk
  const int nwg = gridDim.x;
  const int o = blockIdx.x;
  const int q = nwg >> 3, r = nwg & 7;
  const int xcd = o & 7;
  const int wg = (xcd < r ? xcd * (q + 1) : r * (q + 1) + (xcd - r) * q) + (o >> 3);
  const int rowBase = (wg / NBLK) * 128;
  const int nBase = (wg % NBLK) * 128;
  const int z = (MODE == 0) ? blockIdx.z : 0;
  const unsigned short* BpF = (MODE == 0) ? (B + (size_t)z * 524288) : B;  // z*128*512*8

  __shared__ unsigned short As[6][4096];   // 6-slot ring x [128 rows][32 k] bf16, 48KB

  const int tid = threadIdx.x;
  const int lane = tid & 63;
  const int wv = tid >> 6;                 // 0..3; wave owns rows [wv*32, +32), all cols
  const int lr = lane & 15, kg = lane >> 4;

  // A staging (r10 geometry): wave wv stages chunks {2wv,2wv+1},
  // chunk = 16 rows x 32 k = 1KB; lane l -> row chunk*16+(l>>2), k-chunk (l&3)^((l>>4)&3).
  const int srow0 = (wv * 2) * 16 + (lane >> 2);
  const int srow1 = srow0 + 16;
  const int kswz = (((lane & 3) ^ ((lane >> 4) & 3)) * 8);   // elements
  int gar0 = rowBase + srow0; if (gar0 >= M) gar0 = M - 1;
  int gar1 = rowBase + srow1; if (gar1 >= M) gar1 = M - 1;

  // A fragment read slots (2 frags: rows wv*32 + m*16 + lr), involution pair w/ kswz
  int aslot[2];
#pragma unroll
  for (int m = 0; m < 2; ++m) {
    const int ar = wv * 32 + m * 16 + lr;
    aslot[m] = ar * 32 + ((kg ^ ((lr >> 2) & 3)) * 8);
  }

  // B fragment-order offsets: 8 col frags, elem ((c*NC) + j)*8, c = kt*4+kg
  size_t bjoff[8];
#pragma unroll
  for (int n = 0; n < 8; ++n)
    bjoff[n] = (size_t)(nBase + n * 16 + lr) * 8;

  f32x4 acc[2][8] = {};

  auto stageA = [&](int slot, int kt) {
    const int kk0 = kt * 32;
    const unsigned short *a0p, *a1p;
    if (MODE == 0) {
      if (kk0 < INCH) {
        a0p = A + (size_t)gar0 * CATW + z * 512 + kk0 + kswz;
        a1p = A + (size_t)gar1 * CATW + z * 512 + kk0 + kswz;
      } else {
        a0p = A2 + (size_t)gar0 * INCH + (kk0 - INCH) + kswz;
        a1p = A2 + (size_t)gar1 * INCH + (kk0 - INCH) + kswz;
      }
    } else {
      a0p = A + (size_t)gar0 * KTOT + kk0 + kswz;
      a1p = A + (size_t)gar1 * KTOT + kk0 + kswz;
    }
    __builtin_amdgcn_global_load_lds((const void*)a0p, (void*)&As[slot][(wv * 2) * 512], 16, 0, 0);
    __builtin_amdgcn_global_load_lds((const void*)a1p, (void*)&As[slot][(wv * 2 + 1) * 512], 16, 0, 0);
  };

  auto loadB = [&](int kt, bf16x8 (&dst)[8]) {
    const size_t cbase = (size_t)((kt << 2) + kg) * NC * 8;
#pragma unroll
    for (int n = 0; n < 8; ++n)
      dst[n] = *reinterpret_cast<const bf16x8*>(BpF + cbase + bjoff[n]);
  };

  auto mfma16 = [&](const bf16x8 (&af)[2], const bf16x8 (&b)[8]) {
    __builtin_amdgcn_s_setprio(1);
#pragma unroll
    for (int m = 0; m < 2; ++m)
#pragma unroll
      for (int n = 0; n < 8; ++n)
        acc[m][n] = __builtin_amdgcn_mfma_f32_16x16x32_bf16(af[m], b[n], acc[m][n], 0, 0, 0);
    __builtin_amdgcn_s_setprio(0);
  };

  // 2-tile superstep (t even): one barrier per 2 K-tiles (r16-verified ordering)
  auto superstep = [&](int t, bf16x8 (&bP)[8], bf16x8 (&bQ)[8], bool tail) {
    {
      const int slot = t % 6;
      bf16x8 af[2];
#pragma unroll
      for (int m = 0; m < 2; ++m)
        af[m] = *reinterpret_cast<const bf16x8*>(&As[slot][aslot[m]]);
      loadB(t + 1, bQ);                              // B older than stage(t+4)
      if (t + 4 < KT) stageA((t + 4) % 6, t + 4);
      __builtin_amdgcn_sched_barrier(0);
      mfma16(af, bP);
      __builtin_amdgcn_sched_barrier(0);
    }
    {
      const int slot = (t + 1) % 6;
      bf16x8 af[2];
#pragma unroll
      for (int m = 0; m < 2; ++m)
        af[m] = *reinterpret_cast<const bf16x8*>(&As[slot][aslot[m]]);
      if (t + 2 < KT) loadB(t + 2, bP);
      if (t + 5 < KT) stageA((t + 5) % 6, t + 5);
      __builtin_amdgcn_sched_barrier(0);
      mfma16(af, bQ);
      __builtin_amdgcn_sched_barrier(0);
    }
    if (tail) asm volatile("s_waitcnt vmcnt(0)" ::: "memory");
    __builtin_amdgcn_s_barrier();
    __builtin_amdgcn_sched_barrier(0);
  };

  // ---- prologue: B(0) then tiles 0..3 staged; retire B(0)+s(0)+s(1), keep s(2),s(3)
  bf16x8 bP[8], bQ[8];
  loadB(0, bP);
  stageA(0, 0); stageA(1, 1); stageA(2, 2); stageA(3, 3);
  __builtin_amdgcn_sched_barrier(0);
  asm volatile("s_waitcnt vmcnt(4)" ::: "memory");
  __builtin_amdgcn_s_barrier();
  __builtin_amdgcn_sched_barrier(0);

  // main: full-guard supersteps, then 2 tail supersteps with drain
  int t = 0;
  for (; t < KT - 4; t += 2) superstep(t, bP, bQ, false);
  superstep(t, bP, bQ, true); t += 2;
  superstep(t, bP, bQ, true);

  // ---- epilogue: LDS-staged coalesced writes (r15-verified write phase)
  if (MODE == 0) {
    unsigned short* lds16 = &As[0][0];   // 128x128 bf16 tile, col-XOR swizzled
#pragma unroll
    for (int n = 0; n < 8; ++n) {
      const int j = n * 16 + lr;                     // local col 0..127
      const int ch = z * 512 + nBase + j;
      const float bias = p0[ch];
      const float scale = rsqrtf(p2[ch] + BN_EPS) * p3[ch];
      const float rm = p1[ch], be = p4[ch];
#pragma unroll
      for (int m = 0; m < 2; ++m)
#pragma unroll
        for (int rr = 0; rr < 4; ++rr) {
          const int row = wv * 32 + m * 16 + kg * 4 + rr;   // local row
          float v = acc[m][n][rr] + bias;   // SAGE output
          v = fmaxf(v, 0.0f);               // ReLU FIRST (reference order)
          v = (v - rm) * scale + be;        // BN SECOND
          lds16[row * 128 + (j ^ ((row & 7) << 3))] = f2bf(v);
        }
    }
    __syncthreads();
    const int trow = tid >> 4;          // 0..15
    const int cb = tid & 15;            // 16B (8-bf16) col block
#pragma unroll
    for (int p = 0; p < 8; ++p) {
      const int row = p * 16 + trow;
      const int i = rowBase + row;
      if (i < M) {
        const int scb = cb ^ (row & 7);
        uint4 v = *reinterpret_cast<const uint4*>(&lds16[row * 128 + scb * 8]);
        *reinterpret_cast<uint4*>(&hOut[(size_t)i * CATW + z * 512 + nBase + cb * 8]) = v;
      }
    }
  } else {
    float* ldsf = reinterpret_cast<float*>(&As[0][0]);   // 128x64 f32 half-tile (32KB)
#pragma unroll
    for (int hp = 0; hp < 2; ++hp) {
      __syncthreads();
#pragma unroll
      for (int nn = 0; nn < 4; ++nn) {               // frags n = hp*4 + nn
        const int n = hp * 4 + nn;
        const int jl = nn * 16 + lr;                 // 0..63 within half
#pragma unroll
        for (int m = 0; m < 2; ++m)
#pragma unroll
          for (int rr = 0; rr < 4; ++rr) {
            const int row = wv * 32 + m * 16 + kg * 4 + rr;
            ldsf[row * 64 + jl] = acc[m][n][rr];
          }
      }
      __syncthreads();
      const int trow = tid >> 4, cb = tid & 15;
      const int jbase = nBase + hp * 64;
#pragma unroll
      for (int p = 0; p < 8; ++p) {
        const int row = p * 16 + trow;
        const int i = rowBase + row;
        if (i < M) {
          float4 v = *reinterpret_cast<const float4*>(&ldsf[row * 64 + cb * 4]);
          const int j = jbase + cb * 4;
          if (j < 512) {
            pack4(zbOut + (size_t)i * 512 + j, v.x, v.y, v.z, v.w);   // zb bf16
          } else {
            const int jj = j - 512;
            float* dst = (jj < OUTW) ? (fOut2 + (size_t)i * OUTW + jj)
                                     : (fOut2 + (size_t)M * OUTW + (size_t)i * OUTW + (jj - OUTW));
            *reinterpret_cast<float4*>(dst) = v;
          }
        }
      }
    }
  }
}

// ---------------- launch ----------------

extern "C" void kernel_launch(void* const* d_in, const int* in_sizes, int n_in,
                              void* d_out, int out_size, void* d_ws, size_t ws_size,
                              hipStream_t stream) {
  const float* x     = (const float*)d_in[0];
  const int*   ei    = (const int*)d_in[1];
  const int*   ea    = (const int*)d_in[2];
  const float* Wl5   = (const float*)d_in[3];
  const float* Wr5   = (const float*)d_in[4];
  const float* bl5   = (const float*)d_in[5];
  const float* Wmu_l = (const float*)d_in[6];
  const float* Wmu_r = (const float*)d_in[7];
  const float* bmu   = (const float*)d_in[8];
  const float* Wlv_l = (const float*)d_in[9];
  const float* Wlv_r = (const float*)d_in[10];
  const float* blv   = (const float*)d_in[11];
  const float* gamma = (const float*)d_in[12];
  const float* beta  = (const float*)d_in[13];
  const float* rmean = (const float*)d_in[14];
  const float* rvar  = (const float*)d_in[15];
  (void)n_in; (void)out_size;

  const int N = in_sizes[0] / INCH;   // 20000
  const int E = in_sizes[2];          // 100000
  const int NKEY = N * 5;

  // ---- workspace layout (~182 MB) ----
  char* ws = (char*)d_ws;
  size_t off = 0;
  auto take = [&](size_t bytes) { char* p = ws + off; off += (bytes + 255) & ~(size_t)255; return p; };
  unsigned short* hb = (unsigned short*)take((size_t)N * CATW * 2);      // 102.4 MB
  char* U = take((size_t)N * CATW * 2);                                  // 102.4 MB: meanb5, later zb
  unsigned short* xb = (unsigned short*)take((size_t)N * 512 * 2);       // 20.5 MB
  unsigned short* w1p  = (unsigned short*)take((size_t)5 * 128 * 512 * 8 * 2);  // 5.24 MB
  unsigned short* w23p = (unsigned short*)take((size_t)320 * 1024 * 8 * 2);     // 5.24 MB
  int* cntk  = (int*)take((size_t)NKEY * 4);
  int* offs  = (int*)take((size_t)(NKEY + 1) * 4);
  int* fillc = (int*)take((size_t)NKEY * 4);
  int* perm  = (int*)take((size_t)E * 4);
  int* bsum  = (int*)take(256 * 4);
  if (off > ws_size) return;  // diagnostic guard -> clean absmax-488 failure

  unsigned short* meanb5 = (unsigned short*)U;         // [N,5,512] bf16 (layer-1 life)
  unsigned short* zb = (unsigned short*)U;             // [N,512] bf16 (layer-2 life)

  // conversions / packing (fragment-order weights)
  cvt_bf16_kernel<<<dim3((N * INCH / 4 + 255) / 256), 256, 0, stream>>>(x, xb, N * INCH / 4);
  pack_w1p_kernel<<<dim3((5 * 128 * 512 + 255) / 256), 256, 0, stream>>>(Wl5, Wr5, w1p);
  pack_w23p_kernel<<<dim3((320 * 1024 + 255) / 256), 256, 0, stream>>>(Wmu_l, Wlv_l, Wmu_r, Wlv_r, w23p);

  // CSR build: key = dst*5 + rel
  hipMemsetAsync(cntk, 0, (size_t)NKEY * 4, stream);
  hipMemsetAsync(fillc, 0, (size_t)NKEY * 4, stream);
  hist_kernel<<<dim3((E + 255) / 256), 256, 0, stream>>>(ei, ea, cntk, E);
  const int nb = (NKEY + TS - 1) / TS;
  scan1_kernel<<<dim3(nb), 256, 0, stream>>>(cntk, offs, bsum, NKEY);
  scan2_kernel<<<dim3(1), 128, 0, stream>>>(bsum, nb);
  scan3_kernel<<<dim3((NKEY / 4 + 255) / 256 + 1), 256, 0, stream>>>(offs, bsum, NKEY, E);
  fill_kernel<<<dim3((E + 255) / 256), 256, 0, stream>>>(ei, ea, offs, fillc, perm, E);

  // layer 1: all 5 relation means (one block per node), then ONE batched GEMM dispatch
  gather1_kernel<<<dim3(N), 128, 0, stream>>>(xb, offs, perm, meanb5);
  const int mblk = (N + 127) / 128;    // 157 row-tiles of 128
  gemm_kernel<0><<<dim3(mblk * 4, 1, 5), 256, 0, stream>>>(
      meanb5, xb, w1p, hb, nullptr, nullptr,
      bl5, rmean, rvar, gamma, beta, N);

  // layer 2: one pass over hb computes z (->zb bf16) and y3 (->d_out)
  gemm_kernel<1><<<dim3(mblk * 8, 1, 1), 256, 0, stream>>>(
      hb, nullptr, w23p, nullptr, zb, (float*)d_out,
      nullptr, nullptr, nullptr, nullptr, nullptr, N);

  // fused: d_out += segment-mean(zb) + bias
  gather2_kernel<<<dim3(N), 128, 0, stream>>>(zb, offs, perm, (float*)d_out, bmu, blv, N);
}

// Round 18
// 349.673 us; speedup vs baseline: 1.3095x; 1.3095x over previous
//
#include <hip/hip_runtime.h>
#include <stdint.h>

#define INCH 512
#define HIDW 512
#define CATW 2560
#define OUTW 256
#define BN_EPS 1e-5f
#define TS 1024   // scan tile

typedef __bf16 bf16x8 __attribute__((ext_vector_type(8)));
typedef float f32x4 __attribute__((ext_vector_type(4)));

__device__ __forceinline__ unsigned short f2bf(float f) {
  union { float f; unsigned u; } v; v.f = f;
  unsigned r = v.u + 0x7FFFu + ((v.u >> 16) & 1u);   // RNE
  return (unsigned short)(r >> 16);
}

__device__ __forceinline__ float bf2f(unsigned short u) {
  union { unsigned u; float f; } v; v.u = ((unsigned)u) << 16; return v.f;
}

__device__ __forceinline__ void pack4(unsigned short* dst, float a, float b, float c, float d) {
  unsigned lo = (unsigned)f2bf(a) | ((unsigned)f2bf(b) << 16);
  unsigned hi = (unsigned)f2bf(c) | ((unsigned)f2bf(d) << 16);
  *reinterpret_cast<uint2*>(dst) = make_uint2(lo, hi);
}

// ---------------- conversion / packing kernels ----------------

__global__ void cvt_bf16_kernel(const float* __restrict__ in, unsigned short* __restrict__ out, int n4) {
  int g = blockIdx.x * blockDim.x + threadIdx.x;
  if (g >= n4) return;
  int base = g * 4;
  float4 v = *reinterpret_cast<const float4*>(in + base);
  pack4(out + base, v.x, v.y, v.z, v.w);
}

// w1p fragment-order: elem ((z*128 + c)*512 + j)*8 + e  =  W1[z][j][c*8+e]
__global__ void pack_w1p_kernel(const float* __restrict__ Wl, const float* __restrict__ Wr,
                                unsigned short* __restrict__ out) {
  int g = blockIdx.x * blockDim.x + threadIdx.x;
  if (g >= 5 * 128 * 512) return;
  int z = g >> 16;
  int rem = g & 65535;
  int c = rem >> 9;             // 0..127
  int j = rem & 511;
  int kk = c * 8;
  const float* src = (kk < 512) ? (Wl + ((size_t)(z * 512 + j)) * 512 + kk)
                                : (Wr + ((size_t)(z * 512 + j)) * 512 + (kk - 512));
  float4 a = *reinterpret_cast<const float4*>(src);
  float4 b = *reinterpret_cast<const float4*>(src + 4);
  pack4(out + (size_t)g * 8, a.x, a.y, a.z, a.w);
  pack4(out + (size_t)g * 8 + 4, b.x, b.y, b.z, b.w);
}

// w23p fragment-order: elem (c*1024 + j)*8 + e = W23[j][c*8+e]
__global__ void pack_w23p_kernel(const float* __restrict__ Wmu_l, const float* __restrict__ Wlv_l,
                                 const float* __restrict__ Wmu_r, const float* __restrict__ Wlv_r,
                                 unsigned short* __restrict__ out) {
  int g = blockIdx.x * blockDim.x + threadIdx.x;
  if (g >= 320 * 1024) return;
  int c = g >> 10;              // 0..319
  int j = g & 1023;
  const float* row;
  if (j < 256)       row = Wmu_l + (size_t)j * CATW;
  else if (j < 512)  row = Wlv_l + (size_t)(j - 256) * CATW;
  else if (j < 768)  row = Wmu_r + (size_t)(j - 512) * CATW;
  else               row = Wlv_r + (size_t)(j - 768) * CATW;
  const float* src = row + c * 8;
  float4 a = *reinterpret_cast<const float4*>(src);
  float4 b = *reinterpret_cast<const float4*>(src + 4);
  pack4(out + (size_t)g * 8, a.x, a.y, a.z, a.w);
  pack4(out + (size_t)g * 8 + 4, b.x, b.y, b.z, b.w);
}

// ---------------- CSR build: key = dst*5 + rel ----------------

__global__ void hist_kernel(const int* __restrict__ ei, const int* __restrict__ ea,
                            int* __restrict__ cnt, int E) {
  int e = blockIdx.x * 256 + threadIdx.x;
  if (e >= E) return;
  atomicAdd(&cnt[ei[E + e] * 5 + ea[e]], 1);
}

__global__ void scan1_kernel(const int* __restrict__ in, int* __restrict__ out,
                             int* __restrict__ bsum, int n) {
  __shared__ int lds[256];
  int t = threadIdx.x;
  int base = blockIdx.x * TS + t * 4;
  int4 v = make_int4(0, 0, 0, 0);
  if (base + 3 < n) v = *reinterpret_cast<const int4*>(in + base);
  else {
    if (base < n) v.x = in[base];
    if (base + 1 < n) v.y = in[base + 1];
    if (base + 2 < n) v.z = in[base + 2];
    if (base + 3 < n) v.w = in[base + 3];
  }
  int s = v.x + v.y + v.z + v.w;
  lds[t] = s;
  __syncthreads();
  for (int o = 1; o < 256; o <<= 1) {
    int a = (t >= o) ? lds[t - o] : 0;
    __syncthreads();
    lds[t] += a;
    __syncthreads();
  }
  int excl = lds[t] - s;
  if (t == 255) bsum[blockIdx.x] = lds[255];
  int e0 = excl, e1 = e0 + v.x, e2 = e1 + v.y, e3 = e2 + v.z;
  if (base < n) out[base] = e0;
  if (base + 1 < n) out[base + 1] = e1;
  if (base + 2 < n) out[base + 2] = e2;
  if (base + 3 < n) out[base + 3] = e3;
}

__global__ void scan2_kernel(int* __restrict__ bsum, int nb) {   // nb <= 128
  __shared__ int lds[128];
  int t = threadIdx.x;
  int v = (t < nb) ? bsum[t] : 0;
  lds[t] = v;
  __syncthreads();
  for (int o = 1; o < 128; o <<= 1) {
    int a = (t >= o) ? lds[t - o] : 0;
    __syncthreads();
    lds[t] += a;
    __syncthreads();
  }
  if (t < nb) bsum[t] = lds[t] - v;   // exclusive
}

__global__ void scan3_kernel(int* __restrict__ out, const int* __restrict__ bsum,
                             int n, int total) {
  int g = blockIdx.x * 256 + threadIdx.x;
  if (g == 0) out[n] = total;
  int base = g * 4;
  if (base >= n) return;
  int add = bsum[base / TS];
  if (base + 3 < n) {
    int4 v = *reinterpret_cast<int4*>(out + base);
    v.x += add; v.y += add; v.z += add; v.w += add;
    *reinterpret_cast<int4*>(out + base) = v;
  } else {
    for (int q = 0; q < 4 && base + q < n; ++q) out[base + q] += add;
  }
}

__global__ void fill_kernel(const int* __restrict__ ei, const int* __restrict__ ea,
                            const int* __restrict__ offs, int* __restrict__ fillc,
                            int* __restrict__ perm, int E) {
  int e = blockIdx.x * 256 + threadIdx.x;
  if (e >= E) return;
  int key = ei[E + e] * 5 + ea[e];
  int p = atomicAdd(&fillc[key], 1);
  perm[offs[key] + p] = ei[e];   // store src
}

// ---------------- gather kernels (no atomics) ----------------

// one block per node: all 5 relation means, 5KB contiguous write
__global__ void gather1_kernel(const unsigned short* __restrict__ xb, const int* __restrict__ offs,
                               const int* __restrict__ perm, unsigned short* __restrict__ meanb5) {
  int i = blockIdx.x;
  int t = threadIdx.x;
#pragma unroll
  for (int k = 0; k < 5; ++k) {
    int b0 = offs[i * 5 + k], b1 = offs[i * 5 + k + 1];
    float a0 = 0.f, a1 = 0.f, a2 = 0.f, a3 = 0.f;
    for (int e = b0; e < b1; ++e) {
      int s = perm[e];
      ushort4 v = reinterpret_cast<const ushort4*>(xb + (size_t)s * 512)[t];
      a0 += bf2f(v.x); a1 += bf2f(v.y); a2 += bf2f(v.z); a3 += bf2f(v.w);
    }
    float inv = (b1 > b0) ? 1.0f / (float)(b1 - b0) : 0.0f;
    pack4(meanb5 + (size_t)i * CATW + k * 512 + t * 4, a0 * inv, a1 * inv, a2 * inv, a3 * inv);
  }
}

// fused: d_out += segment-mean(z, bf16) + bias   (mu cols 0..255, logvar cols 256..511)
__global__ void gather2_kernel(const unsigned short* __restrict__ zb, const int* __restrict__ offs,
                               const int* __restrict__ perm, float* __restrict__ dout,
                               const float* __restrict__ bmu, const float* __restrict__ blv,
                               int M) {
  int i = blockIdx.x;
  int t = threadIdx.x;
  int b0 = offs[i * 5], b1 = offs[i * 5 + 5];
  float a0 = 0.f, a1 = 0.f, a2 = 0.f, a3 = 0.f;
  for (int e = b0; e < b1; ++e) {
    int s = perm[e];
    ushort4 v = reinterpret_cast<const ushort4*>(zb + (size_t)s * 512)[t];
    a0 += bf2f(v.x); a1 += bf2f(v.y); a2 += bf2f(v.z); a3 += bf2f(v.w);
  }
  float inv = (b1 > b0) ? 1.0f / (float)(b1 - b0) : 1.0f;
  int c = t * 4;
  float* op;
  const float* bp;
  if (c < 256) { op = dout + (size_t)i * OUTW + c; bp = bmu + c; }
  else         { op = dout + (size_t)M * OUTW + (size_t)i * OUTW + (c - 256); bp = blv + (c - 256); }
  float4 y = *reinterpret_cast<float4*>(op);
  float4 b = *reinterpret_cast<const float4*>(bp);
  y.x += a0 * inv + b.x; y.y += a1 * inv + b.y;
  y.z += a2 * inv + b.z; y.w += a3 * inv + b.w;
  *reinterpret_cast<float4*>(op) = y;
}

// ---------------- MFMA GEMM: r14 core + 2-tile superstep + LDS-staged coalesced
// epilogue (r16 configuration — best measured: 351.7 us total) ----------------
// 6-slot A ring, B reg ping-pong, 2x2 wave grid, raw s_barrier per superstep.
// MODE 0: z=blockIdx.z; A=[meanb5 z-chunk | xb] (K=1024), B=w1p[z]; bias->ReLU->BN -> hb
// MODE 1: A=hb (K=2560), B=w23p; j<512 -> zb (bf16); j>=512 -> d_out raw
template<int MODE>
__global__ __launch_bounds__(256, 3)
void gemm_kernel(const unsigned short* __restrict__ A,
                 const unsigned short* __restrict__ A2,
                 const unsigned short* __restrict__ B,
                 unsigned short* __restrict__ hOut,
                 unsigned short* __restrict__ zbOut,
                 float* __restrict__ fOut2,
                 const float* __restrict__ p0,   // MODE0: bl5
                 const float* __restrict__ p1,   // MODE0: rmean
                 const float* __restrict__ p2,   // MODE0: rvar
                 const float* __restrict__ p3,   // MODE0: gamma
                 const float* __restrict__ p4,   // MODE0: beta
                 int M)
{
  constexpr int KTOT = (MODE == 0) ? (2 * INCH) : CATW;
  constexpr int KT = KTOT / 32;              // 32 / 80 (divisible by 4)
  constexpr int NBLK = (MODE == 0) ? 4 : 8;  // output cols / 128
  constexpr int NC = (MODE == 0) ? 512 : 1024;   // B col count (fragment-order)

  // bijective XCD-chunked swizzle (m204), col-fastest within an XCD chunk
  const int nwg = gridDim.x;
  const int o = blockIdx.x;
  const int q = nwg >> 3, r = nwg & 7;
  const int xcd = o & 7;
  const int wg = (xcd < r ? xcd * (q + 1) : r * (q + 1) + (xcd - r) * q) + (o >> 3);
  const int rowBase = (wg / NBLK) * 128;
  const int nBase = (wg % NBLK) * 128;
  const int z = (MODE == 0) ? blockIdx.z : 0;
  const unsigned short* BpF = (MODE == 0) ? (B + (size_t)z * 524288) : B;  // z*128*512*8

  __shared__ unsigned short As[6][4096];   // 6-slot ring x [128 rows][32 k] bf16, 48KB

  const int tid = threadIdx.x;
  const int lane = tid & 63;
  const int wv = tid >> 6;                 // 0..3
  const int wr = wv >> 1, wc = wv & 1;
  const int lr = lane & 15, kg = lane >> 4;

  // A staging: wave wv stages chunks {2wv,2wv+1}, chunk = 16 rows x 32 k = 1KB;
  // lane l -> row chunk*16+(l>>2), k-chunk (l&3)^((l>>4)&3) (inverse swizzle at source).
  const int srow0 = (wv * 2) * 16 + (lane >> 2);
  const int srow1 = srow0 + 16;
  const int kswz = (((lane & 3) ^ ((lane >> 4) & 3)) * 8);   // elements
  int gar0 = rowBase + srow0; if (gar0 >= M) gar0 = M - 1;
  int gar1 = rowBase + srow1; if (gar1 >= M) gar1 = M - 1;

  // A fragment read slots: ar*32 + ((kg ^ ((lr>>2)&3))*8)  (involution pair w/ kswz)
  int aslot[4];
#pragma unroll
  for (int m = 0; m < 4; ++m) {
    const int ar = wr * 64 + m * 16 + lr;
    aslot[m] = ar * 32 + ((kg ^ ((lr >> 2) & 3)) * 8);
  }

  // B fragment-order offsets: elem ((c*NC) + j)*8, c = kt*4+kg
  size_t bjoff[4];
#pragma unroll
  for (int n = 0; n < 4; ++n)
    bjoff[n] = (size_t)(nBase + wc * 64 + n * 16 + lr) * 8;

  f32x4 acc[4][4] = {};

  auto stageA = [&](int slot, int kt) {
    const int kk0 = kt * 32;
    const unsigned short *a0p, *a1p;
    if (MODE == 0) {
      if (kk0 < INCH) {
        a0p = A + (size_t)gar0 * CATW + z * 512 + kk0 + kswz;
        a1p = A + (size_t)gar1 * CATW + z * 512 + kk0 + kswz;
      } else {
        a0p = A2 + (size_t)gar0 * INCH + (kk0 - INCH) + kswz;
        a1p = A2 + (size_t)gar1 * INCH + (kk0 - INCH) + kswz;
      }
    } else {
      a0p = A + (size_t)gar0 * KTOT + kk0 + kswz;
      a1p = A + (size_t)gar1 * KTOT + kk0 + kswz;
    }
    __builtin_amdgcn_global_load_lds((const void*)a0p, (void*)&As[slot][(wv * 2) * 512], 16, 0, 0);
    __builtin_amdgcn_global_load_lds((const void*)a1p, (void*)&As[slot][(wv * 2 + 1) * 512], 16, 0, 0);
  };

  auto loadB = [&](int kt, bf16x8 (&dst)[4]) {
    const size_t cbase = (size_t)((kt << 2) + kg) * NC * 8;
#pragma unroll
    for (int n = 0; n < 4; ++n)
      dst[n] = *reinterpret_cast<const bf16x8*>(BpF + cbase + bjoff[n]);
  };

  auto mfma16 = [&](const bf16x8 (&af)[4], const bf16x8 (&b)[4]) {
    __builtin_amdgcn_s_setprio(1);
#pragma unroll
    for (int m = 0; m < 4; ++m)
#pragma unroll
      for (int n = 0; n < 4; ++n)
        acc[m][n] = __builtin_amdgcn_mfma_f32_16x16x32_bf16(af[m], b[n], acc[m][n], 0, 0, 0);
    __builtin_amdgcn_s_setprio(0);
  };

  // 2-tile superstep (t even): one barrier per 2 K-tiles
  auto superstep = [&](int t, bf16x8 (&bP)[4], bf16x8 (&bQ)[4], bool tail) {
    {
      const int slot = t % 6;
      bf16x8 af[4];
#pragma unroll
      for (int m = 0; m < 4; ++m)
        af[m] = *reinterpret_cast<const bf16x8*>(&As[slot][aslot[m]]);
      loadB(t + 1, bQ);                              // B older than stage(t+4)
      if (t + 4 < KT) stageA((t + 4) % 6, t + 4);
      __builtin_amdgcn_sched_barrier(0);
      mfma16(af, bP);
      __builtin_amdgcn_sched_barrier(0);
    }
    {
      const int slot = (t + 1) % 6;
      bf16x8 af[4];
#pragma unroll
      for (int m = 0; m < 4; ++m)
        af[m] = *reinterpret_cast<const bf16x8*>(&As[slot][aslot[m]]);
      if (t + 2 < KT) loadB(t + 2, bP);
      if (t + 5 < KT) stageA((t + 5) % 6, t + 5);
      __builtin_amdgcn_sched_barrier(0);
      mfma16(af, bQ);
      __builtin_amdgcn_sched_barrier(0);
    }
    if (tail) asm volatile("s_waitcnt vmcnt(0)" ::: "memory");
    __builtin_amdgcn_s_barrier();
    __builtin_amdgcn_sched_barrier(0);
  };

  // ---- prologue: B(0) then tiles 0..3 staged; retire B(0)+s(0)+s(1), keep s(2),s(3)
  bf16x8 bP[4], bQ[4];
  loadB(0, bP);
  stageA(0, 0); stageA(1, 1); stageA(2, 2); stageA(3, 3);
  __builtin_amdgcn_sched_barrier(0);
  asm volatile("s_waitcnt vmcnt(4)" ::: "memory");
  __builtin_amdgcn_s_barrier();
  __builtin_amdgcn_sched_barrier(0);

  // main: full-guard supersteps, then 2 tail supersteps with drain
  int t = 0;
  for (; t < KT - 4; t += 2) superstep(t, bP, bQ, false);
  superstep(t, bP, bQ, true); t += 2;
  superstep(t, bP, bQ, true);

  // ---- epilogue: LDS-staged coalesced writes (r15-verified)
  if (MODE == 0) {
    unsigned short* lds16 = &As[0][0];   // 128x128 bf16 tile, col-XOR swizzled
#pragma unroll
    for (int n = 0; n < 4; ++n) {
      const int j = wc * 64 + n * 16 + lr;           // local col
      const int ch = z * 512 + nBase + j;
      const float bias = p0[ch];
      const float scale = rsqrtf(p2[ch] + BN_EPS) * p3[ch];
      const float rm = p1[ch], be = p4[ch];
#pragma unroll
      for (int m = 0; m < 4; ++m)
#pragma unroll
        for (int rr = 0; rr < 4; ++rr) {
          const int row = wr * 64 + m * 16 + kg * 4 + rr;   // local row
          float v = acc[m][n][rr] + bias;   // SAGE output
          v = fmaxf(v, 0.0f);               // ReLU FIRST (reference order)
          v = (v - rm) * scale + be;        // BN SECOND
          lds16[row * 128 + (j ^ ((row & 7) << 3))] = f2bf(v);
        }
    }
    __syncthreads();
    const int trow = tid >> 4;          // 0..15
    const int cb = tid & 15;            // 16B (8-bf16) col block
#pragma unroll
    for (int p = 0; p < 8; ++p) {
      const int row = p * 16 + trow;
      const int i = rowBase + row;
      if (i < M) {
        const int scb = cb ^ (row & 7);
        uint4 v = *reinterpret_cast<const uint4*>(&lds16[row * 128 + scb * 8]);
        *reinterpret_cast<uint4*>(&hOut[(size_t)i * CATW + z * 512 + nBase + cb * 8]) = v;
      }
    }
  } else {
    float* ldsf = reinterpret_cast<float*>(&As[0][0]);   // 128x64 f32 half-tile (32KB)
#pragma unroll
    for (int hp = 0; hp < 2; ++hp) {
      __syncthreads();
      if (wc == hp) {                    // waves wc==hp own cols [hp*64, hp*64+64)
#pragma unroll
        for (int n = 0; n < 4; ++n) {
          const int jl = n * 16 + lr;    // 0..63 within half
#pragma unroll
          for (int m = 0; m < 4; ++m)
#pragma unroll
            for (int rr = 0; rr < 4; ++rr) {
              const int row = wr * 64 + m * 16 + kg * 4 + rr;
              ldsf[row * 64 + jl] = acc[m][n][rr];
            }
        }
      }
      __syncthreads();
      const int trow = tid >> 4, cb = tid & 15;
      const int jbase = nBase + hp * 64;
#pragma unroll
      for (int p = 0; p < 8; ++p) {
        const int row = p * 16 + trow;
        const int i = rowBase + row;
        if (i < M) {
          float4 v = *reinterpret_cast<const float4*>(&ldsf[row * 64 + cb * 4]);
          const int j = jbase + cb * 4;
          if (j < 512) {
            pack4(zbOut + (size_t)i * 512 + j, v.x, v.y, v.z, v.w);   // zb bf16
          } else {
            const int jj = j - 512;
            float* dst = (jj < OUTW) ? (fOut2 + (size_t)i * OUTW + jj)
                                     : (fOut2 + (size_t)M * OUTW + (size_t)i * OUTW + (jj - OUTW));
            *reinterpret_cast<float4*>(dst) = v;
          }
        }
      }
    }
  }
}

// ---------------- launch ----------------

extern "C" void kernel_launch(void* const* d_in, const int* in_sizes, int n_in,
                              void* d_out, int out_size, void* d_ws, size_t ws_size,
                              hipStream_t stream) {
  const float* x     = (const float*)d_in[0];
  const int*   ei    = (const int*)d_in[1];
  const int*   ea    = (const int*)d_in[2];
  const float* Wl5   = (const float*)d_in[3];
  const float* Wr5   = (const float*)d_in[4];
  const float* bl5   = (const float*)d_in[5];
  const float* Wmu_l = (const float*)d_in[6];
  const float* Wmu_r = (const float*)d_in[7];
  const float* bmu   = (const float*)d_in[8];
  const float* Wlv_l = (const float*)d_in[9];
  const float* Wlv_r = (const float*)d_in[10];
  const float* blv   = (const float*)d_in[11];
  const float* gamma = (const float*)d_in[12];
  const float* beta  = (const float*)d_in[13];
  const float* rmean = (const float*)d_in[14];
  const float* rvar  = (const float*)d_in[15];
  (void)n_in; (void)out_size;

  const int N = in_sizes[0] / INCH;   // 20000
  const int E = in_sizes[2];          // 100000
  const int NKEY = N * 5;

  // ---- workspace layout (~182 MB) ----
  char* ws = (char*)d_ws;
  size_t off = 0;
  auto take = [&](size_t bytes) { char* p = ws + off; off += (bytes + 255) & ~(size_t)255; return p; };
  unsigned short* hb = (unsigned short*)take((size_t)N * CATW * 2);      // 102.4 MB
  char* U = take((size_t)N * CATW * 2);                                  // 102.4 MB: meanb5, later zb
  unsigned short* xb = (unsigned short*)take((size_t)N * 512 * 2);       // 20.5 MB
  unsigned short* w1p  = (unsigned short*)take((size_t)5 * 128 * 512 * 8 * 2);  // 5.24 MB
  unsigned short* w23p = (unsigned short*)take((size_t)320 * 1024 * 8 * 2);     // 5.24 MB
  int* cntk  = (int*)take((size_t)NKEY * 4);
  int* offs  = (int*)take((size_t)(NKEY + 1) * 4);
  int* fillc = (int*)take((size_t)NKEY * 4);
  int* perm  = (int*)take((size_t)E * 4);
  int* bsum  = (int*)take(256 * 4);
  if (off > ws_size) return;  // diagnostic guard -> clean absmax-488 failure

  unsigned short* meanb5 = (unsigned short*)U;         // [N,5,512] bf16 (layer-1 life)
  unsigned short* zb = (unsigned short*)U;             // [N,512] bf16 (layer-2 life)

  // conversions / packing (fragment-order weights)
  cvt_bf16_kernel<<<dim3((N * INCH / 4 + 255) / 256), 256, 0, stream>>>(x, xb, N * INCH / 4);
  pack_w1p_kernel<<<dim3((5 * 128 * 512 + 255) / 256), 256, 0, stream>>>(Wl5, Wr5, w1p);
  pack_w23p_kernel<<<dim3((320 * 1024 + 255) / 256), 256, 0, stream>>>(Wmu_l, Wlv_l, Wmu_r, Wlv_r, w23p);

  // CSR build: key = dst*5 + rel
  hipMemsetAsync(cntk, 0, (size_t)NKEY * 4, stream);
  hipMemsetAsync(fillc, 0, (size_t)NKEY * 4, stream);
  hist_kernel<<<dim3((E + 255) / 256), 256, 0, stream>>>(ei, ea, cntk, E);
  const int nb = (NKEY + TS - 1) / TS;
  scan1_kernel<<<dim3(nb), 256, 0, stream>>>(cntk, offs, bsum, NKEY);
  scan2_kernel<<<dim3(1), 128, 0, stream>>>(bsum, nb);
  scan3_kernel<<<dim3((NKEY / 4 + 255) / 256 + 1), 256, 0, stream>>>(offs, bsum, NKEY, E);
  fill_kernel<<<dim3((E + 255) / 256), 256, 0, stream>>>(ei, ea, offs, fillc, perm, E);

  // layer 1: all 5 relation means (one block per node), then ONE batched GEMM dispatch
  gather1_kernel<<<dim3(N), 128, 0, stream>>>(xb, offs, perm, meanb5);
  const int mblk = (N + 127) / 128;    // 157 row-tiles of 128
  gemm_kernel<0><<<dim3(mblk * 4, 1, 5), 256, 0, stream>>>(
      meanb5, xb, w1p, hb, nullptr, nullptr,
      bl5, rmean, rvar, gamma, beta, N);

  // layer 2: one pass over hb computes z (->zb bf16) and y3 (->d_out)
  gemm_kernel<1><<<dim3(mblk * 8, 1, 1), 256, 0, stream>>>(
      hb, nullptr, w23p, nullptr, zb, (float*)d_out,
      nullptr, nullptr, nullptr, nullptr, nullptr, N);

  // fused: d_out += segment-mean(zb) + bias
  gather2_kernel<<<dim3(N), 128, 0, stream>>>(zb, offs, perm, (float*)d_out, bmu, blv, N);
}